// Round 8
// baseline (263.751 us; speedup 1.0000x reference)
//
#include <hip/hip_runtime.h>
#include <hip/hip_fp16.h>
#include <math.h>

#define DEPTH 6
#define NN    128
#define EE    160
#define NF    127
#define DIMM  128
#define INNER 512
#define NNODE 256

typedef _Float16 h2f16 __attribute__((ext_vector_type(2)));

#if defined(__has_builtin)
#if __has_builtin(__builtin_amdgcn_fdot2)
#define HAVE_FDOT2 1
#endif
#endif

__device__ __forceinline__ float fdot2f(h2f16 a, h2f16 b, float c) {
#ifdef HAVE_FDOT2
    return __builtin_amdgcn_fdot2(a, b, c, false);
#else
    return c + (float)a.x * (float)b.x + (float)a.y * (float)b.y;
#endif
}

// ---- direct-to-register weight access, double-buffered across phases ----
// Chunked f16 slab layout (written by k_pre cvt prologue):
//   per-wave slice = 16 KB = 16 chunks x 1 KB; chunk i = K-rows [8i,8i+8) of
//   all 64 lane-columns; lane ln's 16 B at chunk + ln*16. A wave's load of one
//   chunk is a contiguous 1 KB (perfectly coalesced); no cross-lane reuse, so
//   registers only — no LDS staging. Two 16-float4 buffers (wA/wB) alternate:
//   while one is dotted, the other's loads (issued a FULL phase earlier) are
//   in flight. Compiler tracks def-use and emits counted vmcnt waits.

__device__ __forceinline__ void ld16c(float4 w[16], const char* g, int ln) {
#pragma unroll
    for (int i = 0; i < 16; i++)
        w[i] = *(const float4*)(g + (size_t)i * 1024 + ln * 16);
}
// f32 row-major variant for k_pre (16 rows, stride rs bytes).
__device__ __forceinline__ void ldf16s(float4 w[16], const char* g, int rs, int ln) {
#pragma unroll
    for (int r = 0; r < 16; r++)
        w[r] = *(const float4*)(g + (size_t)r * rs + ln * 16);
}

// C=512, K=128. Lane output col = w*64+ln; x = 128 halves broadcast from LDS.
__device__ __forceinline__ float gemv512dot(const __half* s_xh, const float4 w[16]) {
    const float4* X = (const float4*)s_xh;
    float a0 = 0, a1 = 0, a2 = 0, a3 = 0;
#pragma unroll
    for (int i = 0; i < 16; i++) {
        float4 xv = X[i];
        const h2f16* wh = (const h2f16*)&w[i];
        const h2f16* xh = (const h2f16*)&xv;
        a0 = fdot2f(xh[0], wh[0], a0); a1 = fdot2f(xh[1], wh[1], a1);
        a2 = fdot2f(xh[2], wh[2], a2); a3 = fdot2f(xh[3], wh[3], a3);
    }
    return (a0 + a1) + (a2 + a3);
}

// C=128, K=512. Lane: col = w*16+(ln>>2), kq = ln&3 owns rows kq*128+[0,128).
// x kq-padded: half idx = (row>>7)*136 + (row&127). Caller combines 4 partials
// with shfl_xor(1)+shfl_xor(2).
__device__ __forceinline__ float gemv128dot(const __half* s_xp, const float4 w[16],
                                            int ln) {
    const char* Xb = (const char*)s_xp + (ln & 3) * 272;
    float a0 = 0, a1 = 0, a2 = 0, a3 = 0;
#pragma unroll
    for (int i = 0; i < 16; i++) {
        float4 xv = *(const float4*)(Xb + i * 16);
        const h2f16* wh = (const h2f16*)&w[i];
        const h2f16* xh = (const h2f16*)&xv;
        a0 = fdot2f(xh[0], wh[0], a0); a1 = fdot2f(xh[1], wh[1], a1);
        a2 = fdot2f(xh[2], wh[2], a2); a3 = fdot2f(xh[3], wh[3], a3);
    }
    return (a0 + a1) + (a2 + a3);
}

// f32 K-split dot for k_pre. Wave wv owns K-rows [wv*16,+16) of a 256-col half.
__device__ __forceinline__ float4 gemvf32dot(const float* s_xn, const float4 w[16],
                                             int wv) {
    float4 acc = {0, 0, 0, 0};
#pragma unroll
    for (int r = 0; r < 16; r++) {
        float a = s_xn[wv * 16 + r];
        acc.x += a * w[r].x; acc.y += a * w[r].y;
        acc.z += a * w[r].z; acc.w += a * w[r].w;
    }
    return acc;
}

// N-value block reduce (8 waves); results broadcast into vals[].
template <int N>
__device__ __forceinline__ void block_reduce_n(float* vals, float* sbuf) {
#pragma unroll
    for (int off = 32; off > 0; off >>= 1)
#pragma unroll
        for (int q = 0; q < N; q++) vals[q] += __shfl_xor(vals[q], off, 64);
    int wave = threadIdx.x >> 6;
    if ((threadIdx.x & 63) == 0)
#pragma unroll
        for (int q = 0; q < N; q++) sbuf[wave * N + q] = vals[q];
    __syncthreads();
#pragma unroll
    for (int q = 0; q < N; q++) {
        float r = 0.0f;
#pragma unroll
        for (int g = 0; g < 8; g++) r += sbuf[g * N + q];
        vals[q] = r;
    }
    __syncthreads();
}

__device__ __forceinline__ float gelu_exact(float a) {
    return 0.5f * a * (1.0f + erff(a * 0.70710678f));
}

// ---------- k_pre: cvt prologue + sedge precompute + node QKV(0) ----------
__global__ __launch_bounds__(512, 1) void k_pre(
        const int* indices, const float* coords, const int* bonds, const float* noise,
        const float* atom_emb, const float* ln1_g, const float* ln1_b,
        const float* Wq, const float* bq, const float* Wkv, const float* bkv,
        const float* Wo, const float* W1, const float* W2,
        __half* hWq, __half* hWkv, __half* hWo, __half* hW1, __half* hW2,
        float* nodes, float* qb, __half* hk, __half* hv, float* sedgews,
        const float* blin, float* out) {
    int bn = blockIdx.x;
    int b = bn >> 7, i = bn & 127;
    int t  = threadIdx.x;
    int d  = t & 127;
    bool own = (t < 128);
    int w = t >> 6, ln = t & 63;
    __shared__ float scoord[384];
    __shared__ int   sadj[128];
    __shared__ float s_xn[128];
    __shared__ float s_red[48];
    __shared__ float s_part[2048];
    __shared__ float lds_pad[24576];   // force 1 block/CU (LDS > 80 KB)
    if (out == (float*)1) lds_pad[t] = 0.0f;   // never true; keeps pad allocated

    if (bn == 0 && t == 0) out[0] = 256.0f * blin[0];

    // f32 QKV phase table: {q lo, q hi, k lo, k hi, v lo, v hi}
    const char* phB[6] = {(const char*)Wq,            (const char*)Wq + 1024,
                          (const char*)Wkv,           (const char*)Wkv + 1024,
                          (const char*)Wkv + 2048,    (const char*)Wkv + 3072};
    const int phRS[6] = {2048, 2048, 4096, 4096, 4096, 4096};

    // ---- one-time setup: coords, adjacency, masked edge row -> ws ----
    if (t < 3 * NN) scoord[t] = coords[b * 3 * NN + t];
    if (t < NN) sadj[t] = 0;
    __syncthreads();
    if (t < EE) {
        int e0 = bonds[2 * t], e1 = bonds[2 * t + 1];
        if (e0 == i) sadj[e1] = 1;
        if (e1 == i) sadj[e0] = 1;
    }
    __syncthreads();
    if (t < NN) {
        int j = t;
        float msk = sadj[j] ? 1.0f : 0.0f;
        sedgews[bn * 384 + 3 * j + 0] = msk * (scoord[3 * i + 0] - scoord[3 * j + 0]);
        sedgews[bn * 384 + 3 * j + 1] = msk * (scoord[3 * i + 1] - scoord[3 * j + 1]);
        sedgews[bn * 384 + 3 * j + 2] = msk * (scoord[3 * i + 2] - scoord[3 * j + 2]);
    }

    // ---- gather + LN1(0) ----
    float nd = 0.0f;
    if (own) {
        int idx = indices[bn];
        nd = (d < NF) ? atom_emb[idx * NF + d] : noise[0];
        nodes[bn * DIMM + d] = nd;
    }
    {
        float vals[2] = {own ? nd : 0.0f, own ? nd * nd : 0.0f};
        block_reduce_n<2>(vals, s_red);
        float m   = vals[0] * (1.0f / 128.0f);
        float var = vals[1] * (1.0f / 128.0f) - m * m;
        if (own) s_xn[d] = (nd - m) * rsqrtf(var + 1e-5f) * ln1_g[d] + ln1_b[d];
    }

    // ---- cvt prologue: f32 -> chunked transposed f16 slabs (all 6 layers) ----
    for (int u = bn * 512 + t; u < 294912; u += NNODE * 512) {
        int s = u >> 13, within = u & 8191;
        int l = s / 6, m = s % 6;
        const float* src; __half* dst; int ncols, colofs, big;
        if (m == 0)      { src = Wq  + (size_t)l * 65536;  dst = hWq  + (size_t)l * 65536;         ncols = 512;  colofs = 0;   big = 0; }
        else if (m == 1) { src = Wkv + (size_t)l * 131072; dst = hWkv + (size_t)l * 131072;        ncols = 1024; colofs = 0;   big = 0; }
        else if (m == 2) { src = Wkv + (size_t)l * 131072; dst = hWkv + (size_t)l * 131072 + 65536;ncols = 1024; colofs = 512; big = 0; }
        else if (m == 3) { src = W1  + (size_t)l * 65536;  dst = hW1  + (size_t)l * 65536;         ncols = 512;  colofs = 0;   big = 0; }
        else if (m == 4) { src = Wo  + (size_t)l * 65536;  dst = hWo  + (size_t)l * 65536;         ncols = 128;  colofs = 0;   big = 1; }
        else             { src = W2  + (size_t)l * 65536;  dst = hW2  + (size_t)l * 65536;         ncols = 128;  colofs = 0;   big = 1; }
        int rb, col;
        if (!big) { rb = within >> 9; col = within & 511; }
        else      { rb = within >> 7; col = within & 127; }
        int row0 = rb * 8;
        __align__(16) __half tmp[8];
#pragma unroll
        for (int e = 0; e < 8; e++)
            tmp[e] = __float2half(src[(size_t)(row0 + e) * ncols + colofs + col]);
        int dh;
        if (!big) dh = (col >> 6) * 8192 + rb * 512 + (col & 63) * 8;
        else {
            int kq = row0 >> 7, ci = (row0 & 127) >> 3;
            dh = (col >> 4) * 8192 + ci * 512 + ((col & 15) * 4 + kq) * 8;
        }
        *(float4*)&dst[dh] = *(const float4*)tmp;
    }

    // issue phase 0+1 weight loads; latency hides under the barrier + combines
    float4 wA[16], wB[16];
    ldf16s(wA, phB[0] + (size_t)(w * 16) * phRS[0], phRS[0], ln);
    ldf16s(wB, phB[1] + (size_t)(w * 16) * phRS[1], phRS[1], ln);
    __syncthreads();

    // ---- QKV from f32 weights, 6 half-phases, double-buffered registers ----
#define PRE_COMBINE(P)                                                        \
    {                                                                         \
        ((float4*)(s_part + w * 256))[ln] = acc;                              \
        __syncthreads();                                                      \
        if (t < 256) {                                                        \
            float sS = 0.0f;                                                  \
            _Pragma("unroll")                                                 \
            for (int g = 0; g < 8; g++) sS += s_part[g * 256 + t];            \
            int col = ((P) & 1) * 256 + t;                                    \
            if ((P) < 2)      qb[(size_t)bn * INNER + col] = sS + bq[col];    \
            else if ((P) < 4) hk[(size_t)bn * INNER + col] =                  \
                                  __float2half(sS + bkv[col]);                \
            else              hv[(size_t)bn * INNER + col] =                  \
                                  __float2half(sS + bkv[INNER + col]);        \
        }                                                                     \
        __syncthreads();                                                      \
    }

    {
        float4 acc;
        acc = gemvf32dot(s_xn, wA, w);
        ldf16s(wA, phB[2] + (size_t)(w * 16) * phRS[2], phRS[2], ln);
        PRE_COMBINE(0);
        acc = gemvf32dot(s_xn, wB, w);
        ldf16s(wB, phB[3] + (size_t)(w * 16) * phRS[3], phRS[3], ln);
        PRE_COMBINE(1);
        acc = gemvf32dot(s_xn, wA, w);
        ldf16s(wA, phB[4] + (size_t)(w * 16) * phRS[4], phRS[4], ln);
        PRE_COMBINE(2);
        acc = gemvf32dot(s_xn, wB, w);
        ldf16s(wB, phB[5] + (size_t)(w * 16) * phRS[5], phRS[5], ln);
        PRE_COMBINE(3);
        acc = gemvf32dot(s_xn, wA, w);
        PRE_COMBINE(4);
        acc = gemvf32dot(s_xn, wB, w);
        PRE_COMBINE(5);
    }
#undef PRE_COMBINE
}

__global__ __launch_bounds__(512, 1) void k_layer(int l,
        const float* sedgews,
        const float* We, const float* be,
        float* qb, const __half* hkin, const __half* hvin,
        __half* hkout, __half* hvout,
        const __half* hWo, const float* bo, const float* Wg1,
        const float* ln2_g, const float* ln2_b,
        const __half* hW1, const float* b1,
        const __half* hW2, const float* b2,
        const float* Wg2,
        const float* ln1_g, const float* ln1_b,
        const __half* hWq, const float* bq,
        const __half* hWkv, const float* bkv,
        float* nodes, const float* Wlin, float* out) {
    int bn = blockIdx.x;
    int b = bn >> 7;
    int t = threadIdx.x;
    int d = t & 127;
    bool own = (t < 128);
    int w = t >> 6, ln = t & 63;

    __shared__ float sedge[384];
    __shared__ float s_l[64];
    __shared__ __align__(16) __half s_aoh[544];   // kq-padded (4 x 136)
    __shared__ __align__(16) __half s_hh[544];    // kq-padded
    __shared__ __align__(16) __half s_xh[128];
    __shared__ float s_x[128];
    __shared__ float s_red[48];
    __shared__ float s_part[4096];     // attention o-combine only
    __shared__ float lds_pad[24576];   // force 1 block/CU (LDS > 80 KB)
    if (out == (float*)1) lds_pad[t] = 0.0f;
    float* s_o = s_part;

    const char* WoL  = (const char*)hWo + (size_t)l * 131072 + w * 16384;
    const char* W1L  = (const char*)hW1 + (size_t)l * 131072 + w * 16384;
    const char* W2L  = (const char*)hW2 + (size_t)l * 131072 + w * 16384;
    const char* WqnL = (const char*)hWq + (size_t)(l + 1) * 131072 + w * 16384;
    const char* WknL = (const char*)hWkv + (size_t)(l + 1) * 262144 + w * 16384;
    const char* WvnL = (const char*)hWkv + (size_t)(l + 1) * 262144 + 131072 + w * 16384;

    // ---------- attention: wave w owns j in [w*16, w*16+16); 64 lanes = 512 dims ----------
    const float4* qR4 = (const float4*)(qb + (size_t)bn * INNER);
    const float4* WeR = (const float4*)(We + (size_t)l * 3 * INNER);
    float4 qa  = qR4[ln * 2],        qz  = qR4[ln * 2 + 1];
    float4 w0a = WeR[ln * 2],        w0z = WeR[ln * 2 + 1];
    float4 w1a = WeR[128 + ln * 2],  w1z = WeR[129 + ln * 2];
    float4 w2a = WeR[256 + ln * 2],  w2z = WeR[257 + ln * 2];
    float4 bea = ((const float4*)(be + (size_t)l * INNER))[ln * 2];
    float4 bez = ((const float4*)(be + (size_t)l * INNER))[ln * 2 + 1];
    float res = own ? nodes[bn * DIMM + d] : 0.0f;
    h2f16 qh0 = {(_Float16)qa.x, (_Float16)qa.y};
    h2f16 qh1 = {(_Float16)qa.z, (_Float16)qa.w};
    h2f16 qh2 = {(_Float16)qz.x, (_Float16)qz.y};
    h2f16 qh3 = {(_Float16)qz.z, (_Float16)qz.w};
    // per-head q.be (non-bonded j have e == be exactly)
    float c = qa.x * bea.x + qa.y * bea.y + qa.z * bea.z + qa.w * bea.w
            + qz.x * bez.x + qz.y * bez.y + qz.z * bez.z + qz.w * bez.w;
    c += __shfl_xor(c, 1, 64); c += __shfl_xor(c, 2, 64); c += __shfl_xor(c, 4, 64);

    if (t < 384) sedge[t] = sedgews[bn * 384 + t];
    __syncthreads();

    const float4* kR = (const float4*)(hkin + (size_t)b * NN * INNER);   // 8 halves/elt
    const float4* vR = (const float4*)(hvin + (size_t)b * NN * INNER);
    float l_run = 0.0f, S_nb = 0.0f;
    float4 o0 = {0, 0, 0, 0}, o1 = {0, 0, 0, 0};
    int j0 = w * 16;
#pragma unroll
    for (int base = 0; base < 16; base += 4) {
        float4 kraw[4], vraw[4];
#pragma unroll
        for (int p = 0; p < 4; p++) {
            int j = j0 + base + p;
            kraw[p] = kR[j * 64 + ln];
            vraw[p] = vR[j * 64 + ln];
        }
#pragma unroll
        for (int p = 0; p < 4; p++) {
            int j = j0 + base + p;
            const h2f16* kh = (const h2f16*)&kraw[p];
            float s = fdot2f(qh0, kh[0],
                      fdot2f(qh1, kh[1],
                      fdot2f(qh2, kh[2],
                      fdot2f(qh3, kh[3], 0.0f))));
            float ex = sedge[3 * j], ey = sedge[3 * j + 1], ez = sedge[3 * j + 2];
            bool bonded = (ex != 0.0f) || (ey != 0.0f) || (ez != 0.0f);  // wave-uniform
            float4 e0, e1;
            if (bonded) {
                e0.x = bea.x + ex * w0a.x + ey * w1a.x + ez * w2a.x;
                e0.y = bea.y + ex * w0a.y + ey * w1a.y + ez * w2a.y;
                e0.z = bea.z + ex * w0a.z + ey * w1a.z + ez * w2a.z;
                e0.w = bea.w + ex * w0a.w + ey * w1a.w + ez * w2a.w;
                e1.x = bez.x + ex * w0z.x + ey * w1z.x + ez * w2z.x;
                e1.y = bez.y + ex * w0z.y + ey * w1z.y + ez * w2z.y;
                e1.z = bez.z + ex * w0z.z + ey * w1z.z + ez * w2z.z;
                e1.w = bez.w + ex * w0z.w + ey * w1z.w + ez * w2z.w;
                s += qa.x * e0.x + qa.y * e0.y + qa.z * e0.z + qa.w * e0.w
                   + qz.x * e1.x + qz.y * e1.y + qz.z * e1.z + qz.w * e1.w;
            }
            s += __shfl_xor(s, 1, 64);
            s += __shfl_xor(s, 2, 64);
            s += __shfl_xor(s, 4, 64);
            if (!bonded) s += c;
            float pp = __expf(s * 0.125f);
            l_run += pp;
            const __half2* vh = (const __half2*)&vraw[p];
            float2 v0 = __half22float2(vh[0]), v1 = __half22float2(vh[1]);
            float2 v2 = __half22float2(vh[2]), v3 = __half22float2(vh[3]);
            o0.x += pp * v0.x; o0.y += pp * v0.y; o0.z += pp * v1.x; o0.w += pp * v1.y;
            o1.x += pp * v2.x; o1.y += pp * v2.y; o1.z += pp * v3.x; o1.w += pp * v3.y;
            if (bonded) {
                o0.x += pp * e0.x; o0.y += pp * e0.y; o0.z += pp * e0.z; o0.w += pp * e0.w;
                o1.x += pp * e1.x; o1.y += pp * e1.y; o1.z += pp * e1.z; o1.w += pp * e1.w;
            } else S_nb += pp;
        }
    }
    // fold the shared be contribution of all non-bonded j
    o0.x += S_nb * bea.x; o0.y += S_nb * bea.y; o0.z += S_nb * bea.z; o0.w += S_nb * bea.w;
    o1.x += S_nb * bez.x; o1.y += S_nb * bez.y; o1.z += S_nb * bez.z; o1.w += S_nb * bez.w;

    // issue Wo AND W1 loads; latency hides under o-combine barriers + Wo phase
    float4 wA[16], wB[16];
    ld16c(wA, WoL, ln);
    ld16c(wB, W1L, ln);

    ((float4*)(s_o + w * 512))[ln * 2]     = o0;
    ((float4*)(s_o + w * 512))[ln * 2 + 1] = o1;
    if ((ln & 7) == 0) s_l[w * 8 + (ln >> 3)] = l_run;
    __syncthreads();
    {
        float o = 0.0f;
#pragma unroll
        for (int g = 0; g < 8; g++) o += s_o[g * 512 + t];
        int h = t >> 6;
        float lsum = 0.0f;
#pragma unroll
        for (int g = 0; g < 8; g++) lsum += s_l[g * 8 + h];
        s_aoh[(t >> 7) * 136 + (t & 127)] = __float2half(o / lsum);
    }
    __syncthreads();

    // ---------- Wo [512 x 128] (refills wA <- W2 after dots) ----------
    {
        float xo = gemv128dot(s_aoh, wA, ln);
        ld16c(wA, W2L, ln);                 // W2 gets gate1 + W1-phase time
        xo += __shfl_xor(xo, 1, 64);
        xo += __shfl_xor(xo, 2, 64);
        if ((ln & 3) == 0) s_x[w * 16 + (ln >> 2)] = xo;
    }
    __syncthreads();
    float x = own ? s_x[d] + bo[l * DIMM + d] : 0.0f;

    // ---------- fused gate1 + LN2 (single reduce pass) ----------
    const float* Wg1_l = Wg1 + l * 3 * DIMM;
    float n1;
    {
        float tex = own ? (x * Wg1_l[d] + res * Wg1_l[DIMM + d]
                           + (x - res) * Wg1_l[2 * DIMM + d]) : 0.0f;
        float vals[6] = {tex,
                         own ? x : 0.0f, own ? x * x : 0.0f,
                         own ? x * res : 0.0f,
                         own ? res : 0.0f, own ? res * res : 0.0f};
        block_reduce_n<6>(vals, s_red);
        float g1 = 1.0f / (1.0f + __expf(-vals[0]));
        float sn  = g1 * vals[1] + (1.0f - g1) * vals[4];
        float sn2 = g1 * g1 * vals[2] + 2.0f * g1 * (1.0f - g1) * vals[3]
                  + (1.0f - g1) * (1.0f - g1) * vals[5];
        float m   = sn * (1.0f / 128.0f);
        float var = sn2 * (1.0f / 128.0f) - m * m;
        n1 = x * g1 + res * (1.0f - g1);
        if (own) s_xh[d] = __float2half((n1 - m) * rsqrtf(var + 1e-5f) * ln2_g[l * DIMM + d]
                                        + ln2_b[l * DIMM + d]);
    }
    __syncthreads();

    // ---------- W1 [128 x 512] + gelu (refills wB <- next Wq) ----------
    {
        float a1 = gemv512dot(s_xh, wB);
        if (l < DEPTH - 1) ld16c(wB, WqnL, ln);   // Wq' gets W2 + gate2 time
        int col = w * 64 + ln;
        float ag = gelu_exact(a1 + b1[l * 4 * DIMM + col]);
        s_hh[(col >> 7) * 136 + (col & 127)] = __float2half(ag);
    }
    __syncthreads();

    // ---------- W2 [512 x 128] (refills wA <- next Wk) ----------
    {
        float yw = gemv128dot(s_hh, wA, ln);
        if (l < DEPTH - 1) ld16c(wA, WknL, ln);   // Wk' gets gate2 + Wq'-phase time
        yw += __shfl_xor(yw, 1, 64);
        yw += __shfl_xor(yw, 2, 64);
        if ((ln & 3) == 0) s_x[w * 16 + (ln >> 2)] = yw;
    }
    __syncthreads();
    float y = own ? s_x[d] + b2[l * DIMM + d] : 0.0f;

    const float* Wg2_l = Wg2 + l * 3 * DIMM;
    if (l < DEPTH - 1) {
        // ---------- fused gate2 + LN1' (single reduce pass) ----------
        float tex = own ? (y * Wg2_l[d] + n1 * Wg2_l[DIMM + d]
                           + (y - n1) * Wg2_l[2 * DIMM + d]) : 0.0f;
        float vals[6] = {tex,
                         own ? y : 0.0f, own ? y * y : 0.0f,
                         own ? y * n1 : 0.0f,
                         own ? n1 : 0.0f, own ? n1 * n1 : 0.0f};
        block_reduce_n<6>(vals, s_red);
        float g2 = 1.0f / (1.0f + __expf(-vals[0]));
        float sn  = g2 * vals[1] + (1.0f - g2) * vals[4];
        float sn2 = g2 * g2 * vals[2] + 2.0f * g2 * (1.0f - g2) * vals[3]
                  + (1.0f - g2) * (1.0f - g2) * vals[5];
        float m   = sn * (1.0f / 128.0f);
        float var = sn2 * (1.0f / 128.0f) - m * m;
        float n2 = y * g2 + n1 * (1.0f - g2);
        if (own) {
            nodes[bn * DIMM + d] = n2;
            s_xh[d] = __float2half((n2 - m) * rsqrtf(var + 1e-5f) * ln1_g[(l + 1) * DIMM + d]
                                   + ln1_b[(l + 1) * DIMM + d]);
        }
        __syncthreads();

        int col = w * 64 + ln;
        // ---------- Wq' / Wk' / Wv' back-to-back, zero barriers ----------
        {
            float q = gemv512dot(s_xh, wB);
            ld16c(wB, WvnL, ln);              // Wv' gets Wq'+Wk' dot time
            qb[(size_t)bn * INNER + col] = q + bq[(l + 1) * INNER + col];
        }
        {
            float kk = gemv512dot(s_xh, wA);
            hkout[(size_t)bn * INNER + col] =
                __float2half(kk + bkv[(l + 1) * 2 * INNER + col]);
        }
        {
            float vv = gemv512dot(s_xh, wB);
            hvout[(size_t)bn * INNER + col] =
                __float2half(vv + bkv[(l + 1) * 2 * INNER + INNER + col]);
        }
    } else {
        // ---------- fused gate2 + final contribution ----------
        float wl = own ? Wlin[d] : 0.0f;
        float tex = own ? (y * Wg2_l[d] + n1 * Wg2_l[DIMM + d]
                           + (y - n1) * Wg2_l[2 * DIMM + d]) : 0.0f;
        float vals[3] = {tex, y * wl, n1 * wl};
        block_reduce_n<3>(vals, s_red);
        float g2 = 1.0f / (1.0f + __expf(-vals[0]));
        float tot = g2 * vals[1] + (1.0f - g2) * vals[2];
        if (t == 0) atomicAdd(out, tot);
    }
}

extern "C" void kernel_launch(void* const* d_in, const int* in_sizes, int n_in,
                              void* d_out, int out_size, void* d_ws, size_t ws_size,
                              hipStream_t stream) {
    const int*   indices = (const int*)d_in[0];
    const float* coords  = (const float*)d_in[1];
    const int*   bonds   = (const int*)d_in[2];
    const float* noise   = (const float*)d_in[3];
    const float* atom_emb= (const float*)d_in[4];
    const float* ln1_g   = (const float*)d_in[5];
    const float* ln1_b   = (const float*)d_in[6];
    const float* Wq      = (const float*)d_in[7];
    const float* bq      = (const float*)d_in[8];
    const float* Wkv     = (const float*)d_in[9];
    const float* bkv     = (const float*)d_in[10];
    const float* We      = (const float*)d_in[11];
    const float* be      = (const float*)d_in[12];
    const float* Wo      = (const float*)d_in[13];
    const float* bo      = (const float*)d_in[14];
    const float* Wg1     = (const float*)d_in[15];
    const float* ln2_g   = (const float*)d_in[16];
    const float* ln2_b   = (const float*)d_in[17];
    const float* W1      = (const float*)d_in[18];
    const float* b1      = (const float*)d_in[19];
    const float* W2      = (const float*)d_in[20];
    const float* b2      = (const float*)d_in[21];
    const float* Wg2     = (const float*)d_in[22];
    const float* Wlin    = (const float*)d_in[23];
    const float* blin    = (const float*)d_in[24];

    float*  ws    = (float*)d_ws;
    float*  nodes = ws;                         // 32768 f
    float*  qb    = nodes + NNODE * DIMM;       // 131072 f
    __half* hkb   = (__half*)(qb + NNODE * INNER);  // 2 slabs x 131072 halves
    __half* hvb   = hkb + 2 * NNODE * INNER;
    __half* hWq   = hvb + 2 * NNODE * INNER;
    __half* hWkv  = hWq + DEPTH * DIMM * INNER;
    __half* hWo   = hWkv + DEPTH * DIMM * 2 * INNER;
    __half* hW1   = hWo + DEPTH * INNER * DIMM;
    __half* hW2   = hW1 + DEPTH * DIMM * 4 * DIMM;
    float*  sedgews = (float*)(hW2 + DEPTH * 4 * DIMM * DIMM);   // 256*384 f

    k_pre<<<NNODE, 512, 0, stream>>>(indices, coords, bonds, noise, atom_emb,
                                     ln1_g, ln1_b, Wq, bq, Wkv, bkv, Wo, W1, W2,
                                     hWq, hWkv, hWo, hW1, hW2,
                                     nodes, qb, hkb, hvb, sedgews, blin, (float*)d_out);
    for (int l = 0; l < DEPTH; l++) {
        const __half* hkin = hkb + (size_t)(l & 1) * NNODE * INNER;
        const __half* hvin = hvb + (size_t)(l & 1) * NNODE * INNER;
        __half* hkout = hkb + (size_t)((l + 1) & 1) * NNODE * INNER;
        __half* hvout = hvb + (size_t)((l + 1) & 1) * NNODE * INNER;
        k_layer<<<NNODE, 512, 0, stream>>>(l, sedgews, We, be,
                                           qb, hkin, hvin, hkout, hvout,
                                           hWo, bo, Wg1, ln2_g, ln2_b, hW1, b1, hW2, b2,
                                           Wg2, ln1_g, ln1_b, hWq, bq, hWkv, bkv,
                                           nodes, Wlin, (float*)d_out);
    }
}

// Round 9
// 263.230 us; speedup vs baseline: 1.0020x; 1.0020x over previous
//
#include <hip/hip_runtime.h>
#include <hip/hip_fp16.h>
#include <math.h>

#define DEPTH 6
#define NN    128
#define EE    160
#define NF    127
#define DIMM  128
#define INNER 512
#define NNODE 256

typedef _Float16 h2f16 __attribute__((ext_vector_type(2)));

#if defined(__has_builtin)
#if __has_builtin(__builtin_amdgcn_fdot2)
#define HAVE_FDOT2 1
#endif
#endif

__device__ __forceinline__ float fdot2f(h2f16 a, h2f16 b, float c) {
#ifdef HAVE_FDOT2
    return __builtin_amdgcn_fdot2(a, b, c, false);
#else
    return c + (float)a.x * (float)b.x + (float)a.y * (float)b.y;
#endif
}

// ---- direct-to-register weight access, double-buffered across phases ----
// Chunked f16 slab layout (written by k_pre cvt prologue):
//   per-wave slice = 16 KB = 16 chunks x 1 KB; chunk i = K-rows [8i,8i+8) of
//   all 64 lane-columns; lane ln's 16 B at chunk + ln*16. A wave's load of one
//   chunk is a contiguous 1 KB (perfectly coalesced); no cross-lane reuse, so
//   registers only — no LDS staging. Two 16-float4 buffers (wA/wB) alternate:
//   while one is dotted, the other's loads (issued a FULL phase earlier) are
//   in flight. Needs ~200 VGPRs: amdgpu_waves_per_eu(2,2) pins the allocator
//   at 2 waves/EU (256-VGPR budget) — round 8 showed that without it the
//   allocator caps at 128 and spills ~14 MB/dispatch to scratch.

__device__ __forceinline__ void ld16c(float4 w[16], const char* g, int ln) {
#pragma unroll
    for (int i = 0; i < 16; i++)
        w[i] = *(const float4*)(g + (size_t)i * 1024 + ln * 16);
}
// f32 row-major variant for k_pre (16 rows, stride rs bytes).
__device__ __forceinline__ void ldf16s(float4 w[16], const char* g, int rs, int ln) {
#pragma unroll
    for (int r = 0; r < 16; r++)
        w[r] = *(const float4*)(g + (size_t)r * rs + ln * 16);
}

// C=512, K=128. Lane output col = w*64+ln; x = 128 halves broadcast from LDS.
__device__ __forceinline__ float gemv512dot(const __half* s_xh, const float4 w[16]) {
    const float4* X = (const float4*)s_xh;
    float a0 = 0, a1 = 0, a2 = 0, a3 = 0;
#pragma unroll
    for (int i = 0; i < 16; i++) {
        float4 xv = X[i];
        const h2f16* wh = (const h2f16*)&w[i];
        const h2f16* xh = (const h2f16*)&xv;
        a0 = fdot2f(xh[0], wh[0], a0); a1 = fdot2f(xh[1], wh[1], a1);
        a2 = fdot2f(xh[2], wh[2], a2); a3 = fdot2f(xh[3], wh[3], a3);
    }
    return (a0 + a1) + (a2 + a3);
}

// C=128, K=512. Lane: col = w*16+(ln>>2), kq = ln&3 owns rows kq*128+[0,128).
// x kq-padded: half idx = (row>>7)*136 + (row&127). Caller combines 4 partials
// with shfl_xor(1)+shfl_xor(2).
__device__ __forceinline__ float gemv128dot(const __half* s_xp, const float4 w[16],
                                            int ln) {
    const char* Xb = (const char*)s_xp + (ln & 3) * 272;
    float a0 = 0, a1 = 0, a2 = 0, a3 = 0;
#pragma unroll
    for (int i = 0; i < 16; i++) {
        float4 xv = *(const float4*)(Xb + i * 16);
        const h2f16* wh = (const h2f16*)&w[i];
        const h2f16* xh = (const h2f16*)&xv;
        a0 = fdot2f(xh[0], wh[0], a0); a1 = fdot2f(xh[1], wh[1], a1);
        a2 = fdot2f(xh[2], wh[2], a2); a3 = fdot2f(xh[3], wh[3], a3);
    }
    return (a0 + a1) + (a2 + a3);
}

// f32 K-split dot for k_pre. Wave wv owns K-rows [wv*16,+16) of a 256-col half.
__device__ __forceinline__ float4 gemvf32dot(const float* s_xn, const float4 w[16],
                                             int wv) {
    float4 acc = {0, 0, 0, 0};
#pragma unroll
    for (int r = 0; r < 16; r++) {
        float a = s_xn[wv * 16 + r];
        acc.x += a * w[r].x; acc.y += a * w[r].y;
        acc.z += a * w[r].z; acc.w += a * w[r].w;
    }
    return acc;
}

// N-value block reduce (8 waves); results broadcast into vals[].
template <int N>
__device__ __forceinline__ void block_reduce_n(float* vals, float* sbuf) {
#pragma unroll
    for (int off = 32; off > 0; off >>= 1)
#pragma unroll
        for (int q = 0; q < N; q++) vals[q] += __shfl_xor(vals[q], off, 64);
    int wave = threadIdx.x >> 6;
    if ((threadIdx.x & 63) == 0)
#pragma unroll
        for (int q = 0; q < N; q++) sbuf[wave * N + q] = vals[q];
    __syncthreads();
#pragma unroll
    for (int q = 0; q < N; q++) {
        float r = 0.0f;
#pragma unroll
        for (int g = 0; g < 8; g++) r += sbuf[g * N + q];
        vals[q] = r;
    }
    __syncthreads();
}

__device__ __forceinline__ float gelu_exact(float a) {
    return 0.5f * a * (1.0f + erff(a * 0.70710678f));
}

// ---------- k_pre: cvt prologue + sedge precompute + node QKV(0) ----------
__global__ __launch_bounds__(512)
__attribute__((amdgpu_waves_per_eu(2, 2)))
void k_pre(
        const int* indices, const float* coords, const int* bonds, const float* noise,
        const float* atom_emb, const float* ln1_g, const float* ln1_b,
        const float* Wq, const float* bq, const float* Wkv, const float* bkv,
        const float* Wo, const float* W1, const float* W2,
        __half* hWq, __half* hWkv, __half* hWo, __half* hW1, __half* hW2,
        float* nodes, float* qb, __half* hk, __half* hv, float* sedgews,
        const float* blin, float* out) {
    int bn = blockIdx.x;
    int b = bn >> 7, i = bn & 127;
    int t  = threadIdx.x;
    int d  = t & 127;
    bool own = (t < 128);
    int w = t >> 6, ln = t & 63;
    __shared__ float scoord[384];
    __shared__ int   sadj[128];
    __shared__ float s_xn[128];
    __shared__ float s_red[48];
    __shared__ float s_part[2048];

    if (bn == 0 && t == 0) out[0] = 256.0f * blin[0];

    // f32 QKV phase table: {q lo, q hi, k lo, k hi, v lo, v hi}
    const char* phB[6] = {(const char*)Wq,            (const char*)Wq + 1024,
                          (const char*)Wkv,           (const char*)Wkv + 1024,
                          (const char*)Wkv + 2048,    (const char*)Wkv + 3072};
    const int phRS[6] = {2048, 2048, 4096, 4096, 4096, 4096};

    // ---- one-time setup: coords, adjacency, masked edge row -> ws ----
    if (t < 3 * NN) scoord[t] = coords[b * 3 * NN + t];
    if (t < NN) sadj[t] = 0;
    __syncthreads();
    if (t < EE) {
        int e0 = bonds[2 * t], e1 = bonds[2 * t + 1];
        if (e0 == i) sadj[e1] = 1;
        if (e1 == i) sadj[e0] = 1;
    }
    __syncthreads();
    if (t < NN) {
        int j = t;
        float msk = sadj[j] ? 1.0f : 0.0f;
        sedgews[bn * 384 + 3 * j + 0] = msk * (scoord[3 * i + 0] - scoord[3 * j + 0]);
        sedgews[bn * 384 + 3 * j + 1] = msk * (scoord[3 * i + 1] - scoord[3 * j + 1]);
        sedgews[bn * 384 + 3 * j + 2] = msk * (scoord[3 * i + 2] - scoord[3 * j + 2]);
    }

    // ---- gather + LN1(0) ----
    float nd = 0.0f;
    if (own) {
        int idx = indices[bn];
        nd = (d < NF) ? atom_emb[idx * NF + d] : noise[0];
        nodes[bn * DIMM + d] = nd;
    }
    {
        float vals[2] = {own ? nd : 0.0f, own ? nd * nd : 0.0f};
        block_reduce_n<2>(vals, s_red);
        float m   = vals[0] * (1.0f / 128.0f);
        float var = vals[1] * (1.0f / 128.0f) - m * m;
        if (own) s_xn[d] = (nd - m) * rsqrtf(var + 1e-5f) * ln1_g[d] + ln1_b[d];
    }

    // ---- cvt prologue: f32 -> chunked transposed f16 slabs (all 6 layers) ----
    for (int u = bn * 512 + t; u < 294912; u += NNODE * 512) {
        int s = u >> 13, within = u & 8191;
        int l = s / 6, m = s % 6;
        const float* src; __half* dst; int ncols, colofs, big;
        if (m == 0)      { src = Wq  + (size_t)l * 65536;  dst = hWq  + (size_t)l * 65536;         ncols = 512;  colofs = 0;   big = 0; }
        else if (m == 1) { src = Wkv + (size_t)l * 131072; dst = hWkv + (size_t)l * 131072;        ncols = 1024; colofs = 0;   big = 0; }
        else if (m == 2) { src = Wkv + (size_t)l * 131072; dst = hWkv + (size_t)l * 131072 + 65536;ncols = 1024; colofs = 512; big = 0; }
        else if (m == 3) { src = W1  + (size_t)l * 65536;  dst = hW1  + (size_t)l * 65536;         ncols = 512;  colofs = 0;   big = 0; }
        else if (m == 4) { src = Wo  + (size_t)l * 65536;  dst = hWo  + (size_t)l * 65536;         ncols = 128;  colofs = 0;   big = 1; }
        else             { src = W2  + (size_t)l * 65536;  dst = hW2  + (size_t)l * 65536;         ncols = 128;  colofs = 0;   big = 1; }
        int rb, col;
        if (!big) { rb = within >> 9; col = within & 511; }
        else      { rb = within >> 7; col = within & 127; }
        int row0 = rb * 8;
        __align__(16) __half tmp[8];
#pragma unroll
        for (int e = 0; e < 8; e++)
            tmp[e] = __float2half(src[(size_t)(row0 + e) * ncols + colofs + col]);
        int dh;
        if (!big) dh = (col >> 6) * 8192 + rb * 512 + (col & 63) * 8;
        else {
            int kq = row0 >> 7, ci = (row0 & 127) >> 3;
            dh = (col >> 4) * 8192 + ci * 512 + ((col & 15) * 4 + kq) * 8;
        }
        *(float4*)&dst[dh] = *(const float4*)tmp;
    }

    // issue phase 0+1 weight loads; latency hides under the barrier + combines
    float4 wA[16], wB[16];
    ldf16s(wA, phB[0] + (size_t)(w * 16) * phRS[0], phRS[0], ln);
    ldf16s(wB, phB[1] + (size_t)(w * 16) * phRS[1], phRS[1], ln);
    __syncthreads();

    // ---- QKV from f32 weights, 6 half-phases, double-buffered registers ----
#define PRE_COMBINE(P)                                                        \
    {                                                                         \
        ((float4*)(s_part + w * 256))[ln] = acc;                              \
        __syncthreads();                                                      \
        if (t < 256) {                                                        \
            float sS = 0.0f;                                                  \
            _Pragma("unroll")                                                 \
            for (int g = 0; g < 8; g++) sS += s_part[g * 256 + t];            \
            int col = ((P) & 1) * 256 + t;                                    \
            if ((P) < 2)      qb[(size_t)bn * INNER + col] = sS + bq[col];    \
            else if ((P) < 4) hk[(size_t)bn * INNER + col] =                  \
                                  __float2half(sS + bkv[col]);                \
            else              hv[(size_t)bn * INNER + col] =                  \
                                  __float2half(sS + bkv[INNER + col]);        \
        }                                                                     \
        __syncthreads();                                                      \
    }

    {
        float4 acc;
        acc = gemvf32dot(s_xn, wA, w);
        ldf16s(wA, phB[2] + (size_t)(w * 16) * phRS[2], phRS[2], ln);
        PRE_COMBINE(0);
        acc = gemvf32dot(s_xn, wB, w);
        ldf16s(wB, phB[3] + (size_t)(w * 16) * phRS[3], phRS[3], ln);
        PRE_COMBINE(1);
        acc = gemvf32dot(s_xn, wA, w);
        ldf16s(wA, phB[4] + (size_t)(w * 16) * phRS[4], phRS[4], ln);
        PRE_COMBINE(2);
        acc = gemvf32dot(s_xn, wB, w);
        ldf16s(wB, phB[5] + (size_t)(w * 16) * phRS[5], phRS[5], ln);
        PRE_COMBINE(3);
        acc = gemvf32dot(s_xn, wA, w);
        PRE_COMBINE(4);
        acc = gemvf32dot(s_xn, wB, w);
        PRE_COMBINE(5);
    }
#undef PRE_COMBINE
}

__global__ __launch_bounds__(512)
__attribute__((amdgpu_waves_per_eu(2, 2)))
void k_layer(int l,
        const float* sedgews,
        const float* We, const float* be,
        float* qb, const __half* hkin, const __half* hvin,
        __half* hkout, __half* hvout,
        const __half* hWo, const float* bo, const float* Wg1,
        const float* ln2_g, const float* ln2_b,
        const __half* hW1, const float* b1,
        const __half* hW2, const float* b2,
        const float* Wg2,
        const float* ln1_g, const float* ln1_b,
        const __half* hWq, const float* bq,
        const __half* hWkv, const float* bkv,
        float* nodes, const float* Wlin, float* out) {
    int bn = blockIdx.x;
    int b = bn >> 7;
    int t = threadIdx.x;
    int d = t & 127;
    bool own = (t < 128);
    int w = t >> 6, ln = t & 63;

    __shared__ float sedge[384];
    __shared__ float s_l[64];
    __shared__ __align__(16) __half s_aoh[544];   // kq-padded (4 x 136)
    __shared__ __align__(16) __half s_hh[544];    // kq-padded
    __shared__ __align__(16) __half s_xh[128];
    __shared__ float s_x[128];
    __shared__ float s_red[48];
    __shared__ float s_part[4096];     // attention o-combine only
    float* s_o = s_part;

    const char* WoL  = (const char*)hWo + (size_t)l * 131072 + w * 16384;
    const char* W1L  = (const char*)hW1 + (size_t)l * 131072 + w * 16384;
    const char* W2L  = (const char*)hW2 + (size_t)l * 131072 + w * 16384;
    const char* WqnL = (const char*)hWq + (size_t)(l + 1) * 131072 + w * 16384;
    const char* WknL = (const char*)hWkv + (size_t)(l + 1) * 262144 + w * 16384;
    const char* WvnL = (const char*)hWkv + (size_t)(l + 1) * 262144 + 131072 + w * 16384;

    // ---------- attention: wave w owns j in [w*16, w*16+16); 64 lanes = 512 dims ----------
    const float4* qR4 = (const float4*)(qb + (size_t)bn * INNER);
    const float4* WeR = (const float4*)(We + (size_t)l * 3 * INNER);
    float4 qa  = qR4[ln * 2],        qz  = qR4[ln * 2 + 1];
    float4 w0a = WeR[ln * 2],        w0z = WeR[ln * 2 + 1];
    float4 w1a = WeR[128 + ln * 2],  w1z = WeR[129 + ln * 2];
    float4 w2a = WeR[256 + ln * 2],  w2z = WeR[257 + ln * 2];
    float4 bea = ((const float4*)(be + (size_t)l * INNER))[ln * 2];
    float4 bez = ((const float4*)(be + (size_t)l * INNER))[ln * 2 + 1];
    float res = own ? nodes[bn * DIMM + d] : 0.0f;
    h2f16 qh0 = {(_Float16)qa.x, (_Float16)qa.y};
    h2f16 qh1 = {(_Float16)qa.z, (_Float16)qa.w};
    h2f16 qh2 = {(_Float16)qz.x, (_Float16)qz.y};
    h2f16 qh3 = {(_Float16)qz.z, (_Float16)qz.w};
    // per-head q.be (non-bonded j have e == be exactly)
    float c = qa.x * bea.x + qa.y * bea.y + qa.z * bea.z + qa.w * bea.w
            + qz.x * bez.x + qz.y * bez.y + qz.z * bez.z + qz.w * bez.w;
    c += __shfl_xor(c, 1, 64); c += __shfl_xor(c, 2, 64); c += __shfl_xor(c, 4, 64);

    if (t < 384) sedge[t] = sedgews[bn * 384 + t];
    __syncthreads();

    const float4* kR = (const float4*)(hkin + (size_t)b * NN * INNER);   // 8 halves/elt
    const float4* vR = (const float4*)(hvin + (size_t)b * NN * INNER);
    float l_run = 0.0f, S_nb = 0.0f;
    float4 o0 = {0, 0, 0, 0}, o1 = {0, 0, 0, 0};
    int j0 = w * 16;
#pragma unroll
    for (int base = 0; base < 16; base += 4) {
        float4 kraw[4], vraw[4];
#pragma unroll
        for (int p = 0; p < 4; p++) {
            int j = j0 + base + p;
            kraw[p] = kR[j * 64 + ln];
            vraw[p] = vR[j * 64 + ln];
        }
#pragma unroll
        for (int p = 0; p < 4; p++) {
            int j = j0 + base + p;
            const h2f16* kh = (const h2f16*)&kraw[p];
            float s = fdot2f(qh0, kh[0],
                      fdot2f(qh1, kh[1],
                      fdot2f(qh2, kh[2],
                      fdot2f(qh3, kh[3], 0.0f))));
            float ex = sedge[3 * j], ey = sedge[3 * j + 1], ez = sedge[3 * j + 2];
            bool bonded = (ex != 0.0f) || (ey != 0.0f) || (ez != 0.0f);  // wave-uniform
            float4 e0, e1;
            if (bonded) {
                e0.x = bea.x + ex * w0a.x + ey * w1a.x + ez * w2a.x;
                e0.y = bea.y + ex * w0a.y + ey * w1a.y + ez * w2a.y;
                e0.z = bea.z + ex * w0a.z + ey * w1a.z + ez * w2a.z;
                e0.w = bea.w + ex * w0a.w + ey * w1a.w + ez * w2a.w;
                e1.x = bez.x + ex * w0z.x + ey * w1z.x + ez * w2z.x;
                e1.y = bez.y + ex * w0z.y + ey * w1z.y + ez * w2z.y;
                e1.z = bez.z + ex * w0z.z + ey * w1z.z + ez * w2z.z;
                e1.w = bez.w + ex * w0z.w + ey * w1z.w + ez * w2z.w;
                s += qa.x * e0.x + qa.y * e0.y + qa.z * e0.z + qa.w * e0.w
                   + qz.x * e1.x + qz.y * e1.y + qz.z * e1.z + qz.w * e1.w;
            }
            s += __shfl_xor(s, 1, 64);
            s += __shfl_xor(s, 2, 64);
            s += __shfl_xor(s, 4, 64);
            if (!bonded) s += c;
            float pp = __expf(s * 0.125f);
            l_run += pp;
            const __half2* vh = (const __half2*)&vraw[p];
            float2 v0 = __half22float2(vh[0]), v1 = __half22float2(vh[1]);
            float2 v2 = __half22float2(vh[2]), v3 = __half22float2(vh[3]);
            o0.x += pp * v0.x; o0.y += pp * v0.y; o0.z += pp * v1.x; o0.w += pp * v1.y;
            o1.x += pp * v2.x; o1.y += pp * v2.y; o1.z += pp * v3.x; o1.w += pp * v3.y;
            if (bonded) {
                o0.x += pp * e0.x; o0.y += pp * e0.y; o0.z += pp * e0.z; o0.w += pp * e0.w;
                o1.x += pp * e1.x; o1.y += pp * e1.y; o1.z += pp * e1.z; o1.w += pp * e1.w;
            } else S_nb += pp;
        }
    }
    // fold the shared be contribution of all non-bonded j
    o0.x += S_nb * bea.x; o0.y += S_nb * bea.y; o0.z += S_nb * bea.z; o0.w += S_nb * bea.w;
    o1.x += S_nb * bez.x; o1.y += S_nb * bez.y; o1.z += S_nb * bez.z; o1.w += S_nb * bez.w;

    // issue Wo AND W1 loads; latency hides under o-combine barriers + Wo phase
    float4 wA[16], wB[16];
    ld16c(wA, WoL, ln);
    ld16c(wB, W1L, ln);

    ((float4*)(s_o + w * 512))[ln * 2]     = o0;
    ((float4*)(s_o + w * 512))[ln * 2 + 1] = o1;
    if ((ln & 7) == 0) s_l[w * 8 + (ln >> 3)] = l_run;
    __syncthreads();
    {
        float o = 0.0f;
#pragma unroll
        for (int g = 0; g < 8; g++) o += s_o[g * 512 + t];
        int h = t >> 6;
        float lsum = 0.0f;
#pragma unroll
        for (int g = 0; g < 8; g++) lsum += s_l[g * 8 + h];
        s_aoh[(t >> 7) * 136 + (t & 127)] = __float2half(o / lsum);
    }
    __syncthreads();

    // ---------- Wo [512 x 128] (refills wA <- W2 after dots) ----------
    {
        float xo = gemv128dot(s_aoh, wA, ln);
        ld16c(wA, W2L, ln);                 // W2 gets gate1 + W1-phase time
        xo += __shfl_xor(xo, 1, 64);
        xo += __shfl_xor(xo, 2, 64);
        if ((ln & 3) == 0) s_x[w * 16 + (ln >> 2)] = xo;
    }
    __syncthreads();
    float x = own ? s_x[d] + bo[l * DIMM + d] : 0.0f;

    // ---------- fused gate1 + LN2 (single reduce pass) ----------
    const float* Wg1_l = Wg1 + l * 3 * DIMM;
    float n1;
    {
        float tex = own ? (x * Wg1_l[d] + res * Wg1_l[DIMM + d]
                           + (x - res) * Wg1_l[2 * DIMM + d]) : 0.0f;
        float vals[6] = {tex,
                         own ? x : 0.0f, own ? x * x : 0.0f,
                         own ? x * res : 0.0f,
                         own ? res : 0.0f, own ? res * res : 0.0f};
        block_reduce_n<6>(vals, s_red);
        float g1 = 1.0f / (1.0f + __expf(-vals[0]));
        float sn  = g1 * vals[1] + (1.0f - g1) * vals[4];
        float sn2 = g1 * g1 * vals[2] + 2.0f * g1 * (1.0f - g1) * vals[3]
                  + (1.0f - g1) * (1.0f - g1) * vals[5];
        float m   = sn * (1.0f / 128.0f);
        float var = sn2 * (1.0f / 128.0f) - m * m;
        n1 = x * g1 + res * (1.0f - g1);
        if (own) s_xh[d] = __float2half((n1 - m) * rsqrtf(var + 1e-5f) * ln2_g[l * DIMM + d]
                                        + ln2_b[l * DIMM + d]);
    }
    __syncthreads();

    // ---------- W1 [128 x 512] + gelu (refills wB <- next Wq) ----------
    {
        float a1 = gemv512dot(s_xh, wB);
        if (l < DEPTH - 1) ld16c(wB, WqnL, ln);   // Wq' gets W2 + gate2 time
        int col = w * 64 + ln;
        float ag = gelu_exact(a1 + b1[l * 4 * DIMM + col]);
        s_hh[(col >> 7) * 136 + (col & 127)] = __float2half(ag);
    }
    __syncthreads();

    // ---------- W2 [512 x 128] (refills wA <- next Wk) ----------
    {
        float yw = gemv128dot(s_hh, wA, ln);
        if (l < DEPTH - 1) ld16c(wA, WknL, ln);   // Wk' gets gate2 + Wq'-phase time
        yw += __shfl_xor(yw, 1, 64);
        yw += __shfl_xor(yw, 2, 64);
        if ((ln & 3) == 0) s_x[w * 16 + (ln >> 2)] = yw;
    }
    __syncthreads();
    float y = own ? s_x[d] + b2[l * DIMM + d] : 0.0f;

    const float* Wg2_l = Wg2 + l * 3 * DIMM;
    if (l < DEPTH - 1) {
        // ---------- fused gate2 + LN1' (single reduce pass) ----------
        float tex = own ? (y * Wg2_l[d] + n1 * Wg2_l[DIMM + d]
                           + (y - n1) * Wg2_l[2 * DIMM + d]) : 0.0f;
        float vals[6] = {tex,
                         own ? y : 0.0f, own ? y * y : 0.0f,
                         own ? y * n1 : 0.0f,
                         own ? n1 : 0.0f, own ? n1 * n1 : 0.0f};
        block_reduce_n<6>(vals, s_red);
        float g2 = 1.0f / (1.0f + __expf(-vals[0]));
        float sn  = g2 * vals[1] + (1.0f - g2) * vals[4];
        float sn2 = g2 * g2 * vals[2] + 2.0f * g2 * (1.0f - g2) * vals[3]
                  + (1.0f - g2) * (1.0f - g2) * vals[5];
        float m   = sn * (1.0f / 128.0f);
        float var = sn2 * (1.0f / 128.0f) - m * m;
        float n2 = y * g2 + n1 * (1.0f - g2);
        if (own) {
            nodes[bn * DIMM + d] = n2;
            s_xh[d] = __float2half((n2 - m) * rsqrtf(var + 1e-5f) * ln1_g[(l + 1) * DIMM + d]
                                   + ln1_b[(l + 1) * DIMM + d]);
        }
        __syncthreads();

        int col = w * 64 + ln;
        // ---------- Wq' / Wk' / Wv' back-to-back, zero barriers ----------
        {
            float q = gemv512dot(s_xh, wB);
            ld16c(wB, WvnL, ln);              // Wv' gets Wq'+Wk' dot time
            qb[(size_t)bn * INNER + col] = q + bq[(l + 1) * INNER + col];
        }
        {
            float kk = gemv512dot(s_xh, wA);
            hkout[(size_t)bn * INNER + col] =
                __float2half(kk + bkv[(l + 1) * 2 * INNER + col]);
        }
        {
            float vv = gemv512dot(s_xh, wB);
            hvout[(size_t)bn * INNER + col] =
                __float2half(vv + bkv[(l + 1) * 2 * INNER + INNER + col]);
        }
    } else {
        // ---------- fused gate2 + final contribution ----------
        float wl = own ? Wlin[d] : 0.0f;
        float tex = own ? (y * Wg2_l[d] + n1 * Wg2_l[DIMM + d]
                           + (y - n1) * Wg2_l[2 * DIMM + d]) : 0.0f;
        float vals[3] = {tex, y * wl, n1 * wl};
        block_reduce_n<3>(vals, s_red);
        float g2 = 1.0f / (1.0f + __expf(-vals[0]));
        float tot = g2 * vals[1] + (1.0f - g2) * vals[2];
        if (t == 0) atomicAdd(out, tot);
    }
}

extern "C" void kernel_launch(void* const* d_in, const int* in_sizes, int n_in,
                              void* d_out, int out_size, void* d_ws, size_t ws_size,
                              hipStream_t stream) {
    const int*   indices = (const int*)d_in[0];
    const float* coords  = (const float*)d_in[1];
    const int*   bonds   = (const int*)d_in[2];
    const float* noise   = (const float*)d_in[3];
    const float* atom_emb= (const float*)d_in[4];
    const float* ln1_g   = (const float*)d_in[5];
    const float* ln1_b   = (const float*)d_in[6];
    const float* Wq      = (const float*)d_in[7];
    const float* bq      = (const float*)d_in[8];
    const float* Wkv     = (const float*)d_in[9];
    const float* bkv     = (const float*)d_in[10];
    const float* We      = (const float*)d_in[11];
    const float* be      = (const float*)d_in[12];
    const float* Wo      = (const float*)d_in[13];
    const float* bo      = (const float*)d_in[14];
    const float* Wg1     = (const float*)d_in[15];
    const float* ln2_g   = (const float*)d_in[16];
    const float* ln2_b   = (const float*)d_in[17];
    const float* W1      = (const float*)d_in[18];
    const float* b1      = (const float*)d_in[19];
    const float* W2      = (const float*)d_in[20];
    const float* b2      = (const float*)d_in[21];
    const float* Wg2     = (const float*)d_in[22];
    const float* Wlin    = (const float*)d_in[23];
    const float* blin    = (const float*)d_in[24];

    float*  ws    = (float*)d_ws;
    float*  nodes = ws;                         // 32768 f
    float*  qb    = nodes + NNODE * DIMM;       // 131072 f
    __half* hkb   = (__half*)(qb + NNODE * INNER);  // 2 slabs x 131072 halves
    __half* hvb   = hkb + 2 * NNODE * INNER;
    __half* hWq   = hvb + 2 * NNODE * INNER;
    __half* hWkv  = hWq + DEPTH * DIMM * INNER;
    __half* hWo   = hWkv + DEPTH * DIMM * 2 * INNER;
    __half* hW1   = hWo + DEPTH * INNER * DIMM;
    __half* hW2   = hW1 + DEPTH * DIMM * 4 * DIMM;
    float*  sedgews = (float*)(hW2 + DEPTH * 4 * DIMM * DIMM);   // 256*384 f

    k_pre<<<NNODE, 512, 0, stream>>>(indices, coords, bonds, noise, atom_emb,
                                     ln1_g, ln1_b, Wq, bq, Wkv, bkv, Wo, W1, W2,
                                     hWq, hWkv, hWo, hW1, hW2,
                                     nodes, qb, hkb, hvb, sedgews, blin, (float*)d_out);
    for (int l = 0; l < DEPTH; l++) {
        const __half* hkin = hkb + (size_t)(l & 1) * NNODE * INNER;
        const __half* hvin = hvb + (size_t)(l & 1) * NNODE * INNER;
        __half* hkout = hkb + (size_t)((l + 1) & 1) * NNODE * INNER;
        __half* hvout = hvb + (size_t)((l + 1) & 1) * NNODE * INNER;
        k_layer<<<NNODE, 512, 0, stream>>>(l, sedgews, We, be,
                                           qb, hkin, hvin, hkout, hvout,
                                           hWo, bo, Wg1, ln2_g, ln2_b, hW1, b1, hW2, b2,
                                           Wg2, ln1_g, ln1_b, hWq, bq, hWkv, bkv,
                                           nodes, Wlin, (float*)d_out);
    }
}

// Round 10
// 229.026 us; speedup vs baseline: 1.1516x; 1.1493x over previous
//
#include <hip/hip_runtime.h>
#include <hip/hip_fp16.h>
#include <math.h>

#define DEPTH 6
#define NN    128
#define EE    160
#define NF    127
#define DIMM  128
#define INNER 512
#define NNODE 256

typedef _Float16 h2f16 __attribute__((ext_vector_type(2)));

#if defined(__has_builtin)
#if __has_builtin(__builtin_amdgcn_fdot2)
#define HAVE_FDOT2 1
#endif
#endif

__device__ __forceinline__ float fdot2f(h2f16 a, h2f16 b, float c) {
#ifdef HAVE_FDOT2
    return __builtin_amdgcn_fdot2(a, b, c, false);
#else
    return c + (float)a.x * (float)b.x + (float)a.y * (float)b.y;
#endif
}

// ---- direct-to-register weight access ----
// Chunked f16 slab layout (written by k_pre cvt prologue):
//   per-wave slice = 16 KB = 16 chunks x 1 KB; chunk i = K-rows [8i,8i+8) of
//   all 64 lane-columns; lane ln's 16 B at chunk + ln*16. A wave's load of one
//   chunk is a contiguous 1 KB (perfectly coalesced). No lane ever reads
//   another lane's bytes -> LDS staging would be pure overhead; registers only.
// Single 64-VGPR buffer with half-phase rolling refill: dot chunks 0-7, issue
// next matrix's chunks 0-7 into the just-freed regs, dot 8-15, issue 8-15.
// Keeps VGPR <= 128 -> 2 blocks/CU co-resident; cross-block overlap does the
// rest of the latency hiding (rounds 8/9 proved double-buffering loses: it
// either spills at the 128-cap or pins occupancy to 1 block/CU at 256).

__device__ __forceinline__ void ld8(float4 w[16], const char* g, int ln, int base) {
#pragma unroll
    for (int i = 0; i < 8; i++)
        w[base + i] = *(const float4*)(g + (size_t)(base + i) * 1024 + ln * 16);
}

__device__ __forceinline__ void dot8h(const float4 w[16], int base, const float4* X,
                                      float& a0, float& a1, float& a2, float& a3) {
#pragma unroll
    for (int i = 0; i < 8; i++) {
        float4 xv = X[base + i];
        const h2f16* wh = (const h2f16*)&w[base + i];
        const h2f16* xh = (const h2f16*)&xv;
        a0 = fdot2f(xh[0], wh[0], a0); a1 = fdot2f(xh[1], wh[1], a1);
        a2 = fdot2f(xh[2], wh[2], a2); a3 = fdot2f(xh[3], wh[3], a3);
    }
}

// C=512, K=128. Lane output col = w*64+ln; x = 128 halves broadcast from LDS.
// Consumes w (current matrix), refills w with nextG chunk-by-chunk mid-chain.
template <int NXT>
__device__ __forceinline__ float gemv512p(const __half* s_xh, float4 w[16],
                                          const char* nextG, int ln) {
    const float4* X = (const float4*)s_xh;
    float a0 = 0, a1 = 0, a2 = 0, a3 = 0;
    dot8h(w, 0, X, a0, a1, a2, a3);
    if (NXT) ld8(w, nextG, ln, 0);        // anti-dep: issues after w[0..7] consumed
    dot8h(w, 8, X, a0, a1, a2, a3);
    if (NXT) ld8(w, nextG, ln, 8);
    return (a0 + a1) + (a2 + a3);
}

// C=128, K=512. Lane: col = w*16+(ln>>2), kq = ln&3 owns rows kq*128+[0,128).
// x kq-padded: half idx = (row>>7)*136 + (row&127). Caller combines 4 partials
// with shfl_xor(1)+shfl_xor(2).
template <int NXT>
__device__ __forceinline__ float gemv128p(const __half* s_xp, float4 w[16],
                                          const char* nextG, int ln) {
    const float4* X = (const float4*)((const char*)s_xp + (ln & 3) * 272);
    float a0 = 0, a1 = 0, a2 = 0, a3 = 0;
    dot8h(w, 0, X, a0, a1, a2, a3);
    if (NXT) ld8(w, nextG, ln, 0);
    dot8h(w, 8, X, a0, a1, a2, a3);
    if (NXT) ld8(w, nextG, ln, 8);
    return (a0 + a1) + (a2 + a3);
}

// f32 K-split unit for k_pre (original row-major f32 weights).
// Wave w owns K-rows [w*16,+16) of a 256-col half; lane ln cols [ln*4,ln*4+4).
__device__ __forceinline__ void ldf8(float4 w[16], const char* g, int rs, int ln, int base) {
#pragma unroll
    for (int r = 0; r < 8; r++)
        w[base + r] = *(const float4*)(g + (size_t)(base + r) * rs + ln * 16);
}
template <int NXT>
__device__ __forceinline__ void gemvf32p(const float* s_xn, float4 w[16],
                                         const char* nextG, int nrs, int wv, int ln,
                                         float4& acc) {
    acc = {0, 0, 0, 0};
#pragma unroll
    for (int r = 0; r < 8; r++) {
        float a = s_xn[wv * 16 + r];
        acc.x += a * w[r].x; acc.y += a * w[r].y;
        acc.z += a * w[r].z; acc.w += a * w[r].w;
    }
    if (NXT) ldf8(w, nextG, nrs, ln, 0);
#pragma unroll
    for (int r = 8; r < 16; r++) {
        float a = s_xn[wv * 16 + r];
        acc.x += a * w[r].x; acc.y += a * w[r].y;
        acc.z += a * w[r].z; acc.w += a * w[r].w;
    }
    if (NXT) ldf8(w, nextG, nrs, ln, 8);
}

// N-value block reduce (8 waves); results broadcast into vals[].
template <int N>
__device__ __forceinline__ void block_reduce_n(float* vals, float* sbuf) {
#pragma unroll
    for (int off = 32; off > 0; off >>= 1)
#pragma unroll
        for (int q = 0; q < N; q++) vals[q] += __shfl_xor(vals[q], off, 64);
    int wave = threadIdx.x >> 6;
    if ((threadIdx.x & 63) == 0)
#pragma unroll
        for (int q = 0; q < N; q++) sbuf[wave * N + q] = vals[q];
    __syncthreads();
#pragma unroll
    for (int q = 0; q < N; q++) {
        float r = 0.0f;
#pragma unroll
        for (int g = 0; g < 8; g++) r += sbuf[g * N + q];
        vals[q] = r;
    }
    __syncthreads();
}

__device__ __forceinline__ float gelu_exact(float a) {
    return 0.5f * a * (1.0f + erff(a * 0.70710678f));
}

// ---------- k_pre: cvt prologue + sedge precompute + node QKV(0) ----------
__global__ __launch_bounds__(512, 1) void k_pre(
        const int* indices, const float* coords, const int* bonds, const float* noise,
        const float* atom_emb, const float* ln1_g, const float* ln1_b,
        const float* Wq, const float* bq, const float* Wkv, const float* bkv,
        const float* Wo, const float* W1, const float* W2,
        __half* hWq, __half* hWkv, __half* hWo, __half* hW1, __half* hW2,
        float* nodes, float* qb, __half* hk, __half* hv, float* sedgews,
        const float* blin, float* out) {
    int bn = blockIdx.x;
    int b = bn >> 7, i = bn & 127;
    int t  = threadIdx.x;
    int d  = t & 127;
    bool own = (t < 128);
    int w = t >> 6, ln = t & 63;
    __shared__ float scoord[384];
    __shared__ int   sadj[128];
    __shared__ float s_xn[128];
    __shared__ float s_red[48];
    __shared__ float s_part[2048];

    if (bn == 0 && t == 0) out[0] = 256.0f * blin[0];

    // f32 QKV phase table: {q lo, q hi, k lo, k hi, v lo, v hi}
    const char* phB[6] = {(const char*)Wq,            (const char*)Wq + 1024,
                          (const char*)Wkv,           (const char*)Wkv + 1024,
                          (const char*)Wkv + 2048,    (const char*)Wkv + 3072};
    const int phRS[6] = {2048, 2048, 4096, 4096, 4096, 4096};

    // ---- one-time setup: coords, adjacency, masked edge row -> ws ----
    if (t < 3 * NN) scoord[t] = coords[b * 3 * NN + t];
    if (t < NN) sadj[t] = 0;
    __syncthreads();
    if (t < EE) {
        int e0 = bonds[2 * t], e1 = bonds[2 * t + 1];
        if (e0 == i) sadj[e1] = 1;
        if (e1 == i) sadj[e0] = 1;
    }
    __syncthreads();
    if (t < NN) {
        int j = t;
        float msk = sadj[j] ? 1.0f : 0.0f;
        sedgews[bn * 384 + 3 * j + 0] = msk * (scoord[3 * i + 0] - scoord[3 * j + 0]);
        sedgews[bn * 384 + 3 * j + 1] = msk * (scoord[3 * i + 1] - scoord[3 * j + 1]);
        sedgews[bn * 384 + 3 * j + 2] = msk * (scoord[3 * i + 2] - scoord[3 * j + 2]);
    }

    // ---- gather + LN1(0) ----
    float nd = 0.0f;
    if (own) {
        int idx = indices[bn];
        nd = (d < NF) ? atom_emb[idx * NF + d] : noise[0];
        nodes[bn * DIMM + d] = nd;
    }
    {
        float vals[2] = {own ? nd : 0.0f, own ? nd * nd : 0.0f};
        block_reduce_n<2>(vals, s_red);
        float m   = vals[0] * (1.0f / 128.0f);
        float var = vals[1] * (1.0f / 128.0f) - m * m;
        if (own) s_xn[d] = (nd - m) * rsqrtf(var + 1e-5f) * ln1_g[d] + ln1_b[d];
    }

    // ---- cvt prologue: f32 -> chunked transposed f16 slabs (all 6 layers) ----
    for (int u = bn * 512 + t; u < 294912; u += NNODE * 512) {
        int s = u >> 13, within = u & 8191;
        int l = s / 6, m = s % 6;
        const float* src; __half* dst; int ncols, colofs, big;
        if (m == 0)      { src = Wq  + (size_t)l * 65536;  dst = hWq  + (size_t)l * 65536;         ncols = 512;  colofs = 0;   big = 0; }
        else if (m == 1) { src = Wkv + (size_t)l * 131072; dst = hWkv + (size_t)l * 131072;        ncols = 1024; colofs = 0;   big = 0; }
        else if (m == 2) { src = Wkv + (size_t)l * 131072; dst = hWkv + (size_t)l * 131072 + 65536;ncols = 1024; colofs = 512; big = 0; }
        else if (m == 3) { src = W1  + (size_t)l * 65536;  dst = hW1  + (size_t)l * 65536;         ncols = 512;  colofs = 0;   big = 0; }
        else if (m == 4) { src = Wo  + (size_t)l * 65536;  dst = hWo  + (size_t)l * 65536;         ncols = 128;  colofs = 0;   big = 1; }
        else             { src = W2  + (size_t)l * 65536;  dst = hW2  + (size_t)l * 65536;         ncols = 128;  colofs = 0;   big = 1; }
        int rb, col;
        if (!big) { rb = within >> 9; col = within & 511; }
        else      { rb = within >> 7; col = within & 127; }
        int row0 = rb * 8;
        __align__(16) __half tmp[8];
#pragma unroll
        for (int e = 0; e < 8; e++)
            tmp[e] = __float2half(src[(size_t)(row0 + e) * ncols + colofs + col]);
        int dh;
        if (!big) dh = (col >> 6) * 8192 + rb * 512 + (col & 63) * 8;
        else {
            int kq = row0 >> 7, ci = (row0 & 127) >> 3;
            dh = (col >> 4) * 8192 + ci * 512 + ((col & 15) * 4 + kq) * 8;
        }
        *(float4*)&dst[dh] = *(const float4*)tmp;
    }

    // issue phase-0 weight loads; latency hides under the barrier + combine
    float4 wr[16];
    ldf8(wr, phB[0] + (size_t)(w * 16) * phRS[0], phRS[0], ln, 0);
    ldf8(wr, phB[0] + (size_t)(w * 16) * phRS[0], phRS[0], ln, 8);
    __syncthreads();

    // ---- QKV from f32 weights, 6 half-phases, rolling register window ----
#define PRE_COMBINE(P)                                                        \
    {                                                                         \
        ((float4*)(s_part + w * 256))[ln] = acc;                              \
        __syncthreads();                                                      \
        if (t < 256) {                                                        \
            float sS = 0.0f;                                                  \
            _Pragma("unroll")                                                 \
            for (int g = 0; g < 8; g++) sS += s_part[g * 256 + t];            \
            int col = ((P) & 1) * 256 + t;                                    \
            if ((P) < 2)      qb[(size_t)bn * INNER + col] = sS + bq[col];    \
            else if ((P) < 4) hk[(size_t)bn * INNER + col] =                  \
                                  __float2half(sS + bkv[col]);                \
            else              hv[(size_t)bn * INNER + col] =                  \
                                  __float2half(sS + bkv[INNER + col]);        \
        }                                                                     \
        __syncthreads();                                                      \
    }

    {
        float4 acc;
        gemvf32p<1>(s_xn, wr, phB[1] + (size_t)(w * 16) * phRS[1], phRS[1], w, ln, acc);
        PRE_COMBINE(0);
        gemvf32p<1>(s_xn, wr, phB[2] + (size_t)(w * 16) * phRS[2], phRS[2], w, ln, acc);
        PRE_COMBINE(1);
        gemvf32p<1>(s_xn, wr, phB[3] + (size_t)(w * 16) * phRS[3], phRS[3], w, ln, acc);
        PRE_COMBINE(2);
        gemvf32p<1>(s_xn, wr, phB[4] + (size_t)(w * 16) * phRS[4], phRS[4], w, ln, acc);
        PRE_COMBINE(3);
        gemvf32p<1>(s_xn, wr, phB[5] + (size_t)(w * 16) * phRS[5], phRS[5], w, ln, acc);
        PRE_COMBINE(4);
        gemvf32p<0>(s_xn, wr, nullptr, 0, w, ln, acc);
        PRE_COMBINE(5);
    }
#undef PRE_COMBINE
}

__global__ __launch_bounds__(512, 1) void k_layer(int l,
        const float* sedgews,
        const float* We, const float* be,
        float* qb, const __half* hkin, const __half* hvin,
        __half* hkout, __half* hvout,
        const __half* hWo, const float* bo, const float* Wg1,
        const float* ln2_g, const float* ln2_b,
        const __half* hW1, const float* b1,
        const __half* hW2, const float* b2,
        const float* Wg2,
        const float* ln1_g, const float* ln1_b,
        const __half* hWq, const float* bq,
        const __half* hWkv, const float* bkv,
        float* nodes, const float* Wlin, float* out) {
    int bn = blockIdx.x;
    int b = bn >> 7;
    int t = threadIdx.x;
    int d = t & 127;
    bool own = (t < 128);
    int w = t >> 6, ln = t & 63;

    __shared__ float sedge[384];
    __shared__ float s_l[64];
    __shared__ __align__(16) __half s_aoh[544];   // kq-padded (4 x 136)
    __shared__ __align__(16) __half s_hh[544];    // kq-padded
    __shared__ __align__(16) __half s_xh[128];
    __shared__ float s_x[128];
    __shared__ float s_red[48];
    __shared__ float s_part[4096];     // attention o-combine only
    float* s_o = s_part;

    const char* WoL  = (const char*)hWo + (size_t)l * 131072 + w * 16384;
    const char* W1L  = (const char*)hW1 + (size_t)l * 131072 + w * 16384;
    const char* W2L  = (const char*)hW2 + (size_t)l * 131072 + w * 16384;
    const char* WqnL = (const char*)hWq + (size_t)(l + 1) * 131072 + w * 16384;
    const char* WknL = (const char*)hWkv + (size_t)(l + 1) * 262144 + w * 16384;
    const char* WvnL = (const char*)hWkv + (size_t)(l + 1) * 262144 + 131072 + w * 16384;

    // ---------- attention: wave w owns j in [w*16, w*16+16); 64 lanes = 512 dims ----------
    const float4* qR4 = (const float4*)(qb + (size_t)bn * INNER);
    const float4* WeR = (const float4*)(We + (size_t)l * 3 * INNER);
    float4 qa  = qR4[ln * 2],        qz  = qR4[ln * 2 + 1];
    float4 w0a = WeR[ln * 2],        w0z = WeR[ln * 2 + 1];
    float4 w1a = WeR[128 + ln * 2],  w1z = WeR[129 + ln * 2];
    float4 w2a = WeR[256 + ln * 2],  w2z = WeR[257 + ln * 2];
    float4 bea = ((const float4*)(be + (size_t)l * INNER))[ln * 2];
    float4 bez = ((const float4*)(be + (size_t)l * INNER))[ln * 2 + 1];
    float res = own ? nodes[bn * DIMM + d] : 0.0f;
    h2f16 qh0 = {(_Float16)qa.x, (_Float16)qa.y};
    h2f16 qh1 = {(_Float16)qa.z, (_Float16)qa.w};
    h2f16 qh2 = {(_Float16)qz.x, (_Float16)qz.y};
    h2f16 qh3 = {(_Float16)qz.z, (_Float16)qz.w};
    // per-head q.be (non-bonded j have e == be exactly)
    float c = qa.x * bea.x + qa.y * bea.y + qa.z * bea.z + qa.w * bea.w
            + qz.x * bez.x + qz.y * bez.y + qz.z * bez.z + qz.w * bez.w;
    c += __shfl_xor(c, 1, 64); c += __shfl_xor(c, 2, 64); c += __shfl_xor(c, 4, 64);

    if (t < 384) sedge[t] = sedgews[bn * 384 + t];
    __syncthreads();

    const float4* kR = (const float4*)(hkin + (size_t)b * NN * INNER);   // 8 halves/elt
    const float4* vR = (const float4*)(hvin + (size_t)b * NN * INNER);
    float l_run = 0.0f, S_nb = 0.0f;
    float4 o0 = {0, 0, 0, 0}, o1 = {0, 0, 0, 0};
    int j0 = w * 16;
#pragma unroll
    for (int base = 0; base < 16; base += 4) {
        float4 kraw[4], vraw[4];
#pragma unroll
        for (int p = 0; p < 4; p++) {
            int j = j0 + base + p;
            kraw[p] = kR[j * 64 + ln];
            vraw[p] = vR[j * 64 + ln];
        }
#pragma unroll
        for (int p = 0; p < 4; p++) {
            int j = j0 + base + p;
            const h2f16* kh = (const h2f16*)&kraw[p];
            float s = fdot2f(qh0, kh[0],
                      fdot2f(qh1, kh[1],
                      fdot2f(qh2, kh[2],
                      fdot2f(qh3, kh[3], 0.0f))));
            float ex = sedge[3 * j], ey = sedge[3 * j + 1], ez = sedge[3 * j + 2];
            bool bonded = (ex != 0.0f) || (ey != 0.0f) || (ez != 0.0f);  // wave-uniform
            float4 e0, e1;
            if (bonded) {
                e0.x = bea.x + ex * w0a.x + ey * w1a.x + ez * w2a.x;
                e0.y = bea.y + ex * w0a.y + ey * w1a.y + ez * w2a.y;
                e0.z = bea.z + ex * w0a.z + ey * w1a.z + ez * w2a.z;
                e0.w = bea.w + ex * w0a.w + ey * w1a.w + ez * w2a.w;
                e1.x = bez.x + ex * w0z.x + ey * w1z.x + ez * w2z.x;
                e1.y = bez.y + ex * w0z.y + ey * w1z.y + ez * w2z.y;
                e1.z = bez.z + ex * w0z.z + ey * w1z.z + ez * w2z.z;
                e1.w = bez.w + ex * w0z.w + ey * w1z.w + ez * w2z.w;
                s += qa.x * e0.x + qa.y * e0.y + qa.z * e0.z + qa.w * e0.w
                   + qz.x * e1.x + qz.y * e1.y + qz.z * e1.z + qz.w * e1.w;
            }
            s += __shfl_xor(s, 1, 64);
            s += __shfl_xor(s, 2, 64);
            s += __shfl_xor(s, 4, 64);
            if (!bonded) s += c;
            float pp = __expf(s * 0.125f);
            l_run += pp;
            const __half2* vh = (const __half2*)&vraw[p];
            float2 v0 = __half22float2(vh[0]), v1 = __half22float2(vh[1]);
            float2 v2 = __half22float2(vh[2]), v3 = __half22float2(vh[3]);
            o0.x += pp * v0.x; o0.y += pp * v0.y; o0.z += pp * v1.x; o0.w += pp * v1.y;
            o1.x += pp * v2.x; o1.y += pp * v2.y; o1.z += pp * v3.x; o1.w += pp * v3.y;
            if (bonded) {
                o0.x += pp * e0.x; o0.y += pp * e0.y; o0.z += pp * e0.z; o0.w += pp * e0.w;
                o1.x += pp * e1.x; o1.y += pp * e1.y; o1.z += pp * e1.z; o1.w += pp * e1.w;
            } else S_nb += pp;
        }
    }
    // fold the shared be contribution of all non-bonded j
    o0.x += S_nb * bea.x; o0.y += S_nb * bea.y; o0.z += S_nb * bea.z; o0.w += S_nb * bea.w;
    o1.x += S_nb * bez.x; o1.y += S_nb * bez.y; o1.z += S_nb * bez.z; o1.w += S_nb * bez.w;

    // issue Wo loads now; latency hides under o-combine barriers below
    float4 wreg[16];
    ld8(wreg, WoL, ln, 0);
    ld8(wreg, WoL, ln, 8);

    ((float4*)(s_o + w * 512))[ln * 2]     = o0;
    ((float4*)(s_o + w * 512))[ln * 2 + 1] = o1;
    if ((ln & 7) == 0) s_l[w * 8 + (ln >> 3)] = l_run;
    __syncthreads();
    {
        float o = 0.0f;
#pragma unroll
        for (int g = 0; g < 8; g++) o += s_o[g * 512 + t];
        int h = t >> 6;
        float lsum = 0.0f;
#pragma unroll
        for (int g = 0; g < 8; g++) lsum += s_l[g * 8 + h];
        s_aoh[(t >> 7) * 136 + (t & 127)] = __float2half(o / lsum);
    }
    __syncthreads();

    // ---------- Wo [512 x 128] (loads W1 mid-chain) ----------
    {
        float xo = gemv128p<1>(s_aoh, wreg, W1L, ln);
        xo += __shfl_xor(xo, 1, 64);
        xo += __shfl_xor(xo, 2, 64);
        if ((ln & 3) == 0) s_x[w * 16 + (ln >> 2)] = xo;
    }
    __syncthreads();
    float x = own ? s_x[d] + bo[l * DIMM + d] : 0.0f;

    // ---------- fused gate1 + LN2 (single reduce pass) ----------
    const float* Wg1_l = Wg1 + l * 3 * DIMM;
    float n1;
    {
        float tex = own ? (x * Wg1_l[d] + res * Wg1_l[DIMM + d]
                           + (x - res) * Wg1_l[2 * DIMM + d]) : 0.0f;
        float vals[6] = {tex,
                         own ? x : 0.0f, own ? x * x : 0.0f,
                         own ? x * res : 0.0f,
                         own ? res : 0.0f, own ? res * res : 0.0f};
        block_reduce_n<6>(vals, s_red);
        float g1 = 1.0f / (1.0f + __expf(-vals[0]));
        float sn  = g1 * vals[1] + (1.0f - g1) * vals[4];
        float sn2 = g1 * g1 * vals[2] + 2.0f * g1 * (1.0f - g1) * vals[3]
                  + (1.0f - g1) * (1.0f - g1) * vals[5];
        float m   = sn * (1.0f / 128.0f);
        float var = sn2 * (1.0f / 128.0f) - m * m;
        n1 = x * g1 + res * (1.0f - g1);
        if (own) s_xh[d] = __float2half((n1 - m) * rsqrtf(var + 1e-5f) * ln2_g[l * DIMM + d]
                                        + ln2_b[l * DIMM + d]);
    }
    __syncthreads();

    // ---------- W1 [128 x 512] + gelu (loads W2 mid-chain) ----------
    {
        float a1 = gemv512p<1>(s_xh, wreg, W2L, ln);
        int col = w * 64 + ln;
        float ag = gelu_exact(a1 + b1[l * 4 * DIMM + col]);
        s_hh[(col >> 7) * 136 + (col & 127)] = __float2half(ag);
    }
    __syncthreads();

    // ---------- W2 [512 x 128] (loads next-layer Wq if needed) ----------
    {
        float yw;
        if (l < DEPTH - 1) yw = gemv128p<1>(s_hh, wreg, WqnL, ln);
        else               yw = gemv128p<0>(s_hh, wreg, nullptr, ln);
        yw += __shfl_xor(yw, 1, 64);
        yw += __shfl_xor(yw, 2, 64);
        if ((ln & 3) == 0) s_x[w * 16 + (ln >> 2)] = yw;
    }
    __syncthreads();
    float y = own ? s_x[d] + b2[l * DIMM + d] : 0.0f;

    const float* Wg2_l = Wg2 + l * 3 * DIMM;
    if (l < DEPTH - 1) {
        // ---------- fused gate2 + LN1' (single reduce pass) ----------
        float tex = own ? (y * Wg2_l[d] + n1 * Wg2_l[DIMM + d]
                           + (y - n1) * Wg2_l[2 * DIMM + d]) : 0.0f;
        float vals[6] = {tex,
                         own ? y : 0.0f, own ? y * y : 0.0f,
                         own ? y * n1 : 0.0f,
                         own ? n1 : 0.0f, own ? n1 * n1 : 0.0f};
        block_reduce_n<6>(vals, s_red);
        float g2 = 1.0f / (1.0f + __expf(-vals[0]));
        float sn  = g2 * vals[1] + (1.0f - g2) * vals[4];
        float sn2 = g2 * g2 * vals[2] + 2.0f * g2 * (1.0f - g2) * vals[3]
                  + (1.0f - g2) * (1.0f - g2) * vals[5];
        float m   = sn * (1.0f / 128.0f);
        float var = sn2 * (1.0f / 128.0f) - m * m;
        float n2 = y * g2 + n1 * (1.0f - g2);
        if (own) {
            nodes[bn * DIMM + d] = n2;
            s_xh[d] = __float2half((n2 - m) * rsqrtf(var + 1e-5f) * ln1_g[(l + 1) * DIMM + d]
                                   + ln1_b[(l + 1) * DIMM + d]);
        }
        __syncthreads();

        int col = w * 64 + ln;
        // ---------- Wq' / Wk' / Wv' back-to-back, zero barriers ----------
        {
            float q = gemv512p<1>(s_xh, wreg, WknL, ln);
            qb[(size_t)bn * INNER + col] = q + bq[(l + 1) * INNER + col];
        }
        {
            float kk = gemv512p<1>(s_xh, wreg, WvnL, ln);
            hkout[(size_t)bn * INNER + col] =
                __float2half(kk + bkv[(l + 1) * 2 * INNER + col]);
        }
        {
            float vv = gemv512p<0>(s_xh, wreg, nullptr, ln);
            hvout[(size_t)bn * INNER + col] =
                __float2half(vv + bkv[(l + 1) * 2 * INNER + INNER + col]);
        }
    } else {
        // ---------- fused gate2 + final contribution ----------
        float wl = own ? Wlin[d] : 0.0f;
        float tex = own ? (y * Wg2_l[d] + n1 * Wg2_l[DIMM + d]
                           + (y - n1) * Wg2_l[2 * DIMM + d]) : 0.0f;
        float vals[3] = {tex, y * wl, n1 * wl};
        block_reduce_n<3>(vals, s_red);
        float g2 = 1.0f / (1.0f + __expf(-vals[0]));
        float tot = g2 * vals[1] + (1.0f - g2) * vals[2];
        if (t == 0) atomicAdd(out, tot);
    }
}

extern "C" void kernel_launch(void* const* d_in, const int* in_sizes, int n_in,
                              void* d_out, int out_size, void* d_ws, size_t ws_size,
                              hipStream_t stream) {
    const int*   indices = (const int*)d_in[0];
    const float* coords  = (const float*)d_in[1];
    const int*   bonds   = (const int*)d_in[2];
    const float* noise   = (const float*)d_in[3];
    const float* atom_emb= (const float*)d_in[4];
    const float* ln1_g   = (const float*)d_in[5];
    const float* ln1_b   = (const float*)d_in[6];
    const float* Wq      = (const float*)d_in[7];
    const float* bq      = (const float*)d_in[8];
    const float* Wkv     = (const float*)d_in[9];
    const float* bkv     = (const float*)d_in[10];
    const float* We      = (const float*)d_in[11];
    const float* be      = (const float*)d_in[12];
    const float* Wo      = (const float*)d_in[13];
    const float* bo      = (const float*)d_in[14];
    const float* Wg1     = (const float*)d_in[15];
    const float* ln2_g   = (const float*)d_in[16];
    const float* ln2_b   = (const float*)d_in[17];
    const float* W1      = (const float*)d_in[18];
    const float* b1      = (const float*)d_in[19];
    const float* W2      = (const float*)d_in[20];
    const float* b2      = (const float*)d_in[21];
    const float* Wg2     = (const float*)d_in[22];
    const float* Wlin    = (const float*)d_in[23];
    const float* blin    = (const float*)d_in[24];

    float*  ws    = (float*)d_ws;
    float*  nodes = ws;                         // 32768 f
    float*  qb    = nodes + NNODE * DIMM;       // 131072 f
    __half* hkb   = (__half*)(qb + NNODE * INNER);  // 2 slabs x 131072 halves
    __half* hvb   = hkb + 2 * NNODE * INNER;
    __half* hWq   = hvb + 2 * NNODE * INNER;
    __half* hWkv  = hWq + DEPTH * DIMM * INNER;
    __half* hWo   = hWkv + DEPTH * DIMM * 2 * INNER;
    __half* hW1   = hWo + DEPTH * INNER * DIMM;
    __half* hW2   = hW1 + DEPTH * DIMM * 4 * DIMM;
    float*  sedgews = (float*)(hW2 + DEPTH * 4 * DIMM * DIMM);   // 256*384 f

    k_pre<<<NNODE, 512, 0, stream>>>(indices, coords, bonds, noise, atom_emb,
                                     ln1_g, ln1_b, Wq, bq, Wkv, bkv, Wo, W1, W2,
                                     hWq, hWkv, hWo, hW1, hW2,
                                     nodes, qb, hkb, hvb, sedgews, blin, (float*)d_out);
    for (int l = 0; l < DEPTH; l++) {
        const __half* hkin = hkb + (size_t)(l & 1) * NNODE * INNER;
        const __half* hvin = hvb + (size_t)(l & 1) * NNODE * INNER;
        __half* hkout = hkb + (size_t)((l + 1) & 1) * NNODE * INNER;
        __half* hvout = hvb + (size_t)((l + 1) & 1) * NNODE * INNER;
        k_layer<<<NNODE, 512, 0, stream>>>(l, sedgews, We, be,
                                           qb, hkin, hvin, hkout, hvout,
                                           hWo, bo, Wg1, ln2_g, ln2_b, hW1, b1, hW2, b2,
                                           Wg2, ln1_g, ln1_b, hWq, bq, hWkv, bkv,
                                           nodes, Wlin, (float*)d_out);
    }
}